// Round 10
// baseline (130.782 us; speedup 1.0000x reference)
//
#include <hip/hip_runtime.h>
#include <math.h>

// SDFNet: conv1x1(1->8) -> 16x (h += minpool3(h)) -> conv3x3(8->32) -> relu -> conv1x1(32->1)
//
// Factorization: erosion steps act per-channel on affine maps of x.
//   w0[c] > 0: h_c after 16 iters = w0[c]*P16(x) + b0[c]*2^16   (P = min-iterate of x)
//   w0[c] < 0: h_c = |w0[c]|*Q16 + b0[c]*2^16, Q = min-iterate of -x (pad +inf exact)
// Head = 3x3 conv over (P,Q) with folded weights (f2 -> v_pk_fma_f32), bias
// beta = 65536*sum_ic b0*w1 applied only for in-image taps (ref zero-pads h):
// row sums D (ry-masked) for all px, col sums EL/ER subtracted at x=0/511 lanes.
//
// R8: cross-lane +/-1 shifts on the VALU pipe via wave-wide DPP; `old` = fill.
// R10: erode restructured to 16 rows/thread (4-wave blocks, same 64-staged/32-valid
// tile -> no extra redundancy): DS instr per CU per step cut 4x (amortized halo +
// f2/b64 SoA, 2-way bank aliasing = free), barrier scope 8->4 waves.

#define N_PIX (512*512)
#define INF __builtin_inff()

typedef __attribute__((ext_vector_type(2))) float f2;

// lane l gets v[l-1]; lane 0 gets `fill`   (DPP wave_shr1 = 0x138, VALU pipe)
__device__ __forceinline__ float dpp_shr1(float v, float fill) {
    return __int_as_float(__builtin_amdgcn_update_dpp(
        __float_as_int(fill), __float_as_int(v), 0x138, 0xF, 0xF, false));
}
// lane l gets v[l+1]; lane 63 gets `fill`  (DPP wave_shl1 = 0x130)
__device__ __forceinline__ float dpp_shl1(float v, float fill) {
    return __int_as_float(__builtin_amdgcn_update_dpp(
        __float_as_int(fill), __float_as_int(v), 0x130, 0xF, 0xF, false));
}

struct Row8 { float4 a, b; };

__device__ __forceinline__ Row8 row_update8(const Row8 up, const Row8 mid, const Row8 dn)
{
    float4 va, vb;
    va.x = fminf(fminf(up.a.x, mid.a.x), dn.a.x);
    va.y = fminf(fminf(up.a.y, mid.a.y), dn.a.y);
    va.z = fminf(fminf(up.a.z, mid.a.z), dn.a.z);
    va.w = fminf(fminf(up.a.w, mid.a.w), dn.a.w);
    vb.x = fminf(fminf(up.b.x, mid.b.x), dn.b.x);
    vb.y = fminf(fminf(up.b.y, mid.b.y), dn.b.y);
    vb.z = fminf(fminf(up.b.z, mid.b.z), dn.b.z);
    vb.w = fminf(fminf(up.b.w, mid.b.w), dn.b.w);
    float vmL = dpp_shr1(vb.w, INF);   // left neighbor vmin; lane0 -> +inf image edge
    float vmR = dpp_shl1(va.x, INF);   // right neighbor vmin; lane63 -> +inf image edge
    float tm1 = fminf(vmL, va.x);
    float t0 = fminf(va.x, va.y), t1 = fminf(va.y, va.z);
    float t2 = fminf(va.z, va.w), t3 = fminf(va.w, vb.x);
    float t4 = fminf(vb.x, vb.y), t5 = fminf(vb.y, vb.z);
    float t6 = fminf(vb.z, vb.w), t7 = fminf(vb.w, vmR);
    Row8 o;
    o.a.x = mid.a.x + fminf(tm1, t0);
    o.a.y = mid.a.y + fminf(t0, t1);
    o.a.z = mid.a.z + fminf(t1, t2);
    o.a.w = mid.a.w + fminf(t2, t3);
    o.b.x = mid.b.x + fminf(t3, t4);
    o.b.y = mid.b.y + fminf(t4, t5);
    o.b.z = mid.b.z + fminf(t5, t6);
    o.b.w = mid.b.w + fminf(t6, t7);
    return o;
}

// f2 SoA halo: lane stride 8B -> 2-way bank aliasing (free, m136); 4 b64 ops per row
__device__ __forceinline__ void halo_write(f2* hp, const Row8& v) {
    hp[0*64] = (f2){v.a.x, v.a.y};
    hp[1*64] = (f2){v.a.z, v.a.w};
    hp[2*64] = (f2){v.b.x, v.b.y};
    hp[3*64] = (f2){v.b.z, v.b.w};
}
__device__ __forceinline__ Row8 halo_read(const f2* hp) {
    f2 p0 = hp[0*64], p1 = hp[1*64], p2 = hp[2*64], p3 = hp[3*64];
    Row8 v;
    v.a = make_float4(p0.x, p0.y, p1.x, p1.y);
    v.b = make_float4(p2.x, p2.y, p3.x, p3.y);
    return v;
}

// ---------------------------------------------------------------- erosion + prep
// W layout (floats):
//   [0..575]        f2 {wp,wq} at index (oc*9+k)  (k = ky*3+kx)
//   [576 + oc*4+r]  D:  r0=rowsum_top(beta), r1=b1+rowsum_mid, r2=rowsum_bot
//   [704 + oc*4+r]  EL: col-0 beta by row (top,mid,bot)
//   [832 + oc*4+r]  ER: col-2 beta by row
__global__ __launch_bounds__(256, 1) void erode16_kernel(
    const float* __restrict__ x, float* __restrict__ A,
    const float* __restrict__ w0, const float* __restrict__ b0,
    const float* __restrict__ w1, const float* __restrict__ b1,
    float* __restrict__ W)
{
    // prep fold (one block; W consumed only by the later head dispatch)
    if (blockIdx.x == 0 && blockIdx.y == 0) {
        for (int t = threadIdx.x; t < 288; t += 256) {
            int oc = t / 9, k = t - oc*9;
            float wp = 0.f, wq = 0.f;
            for (int ic = 0; ic < 8; ++ic) {
                float a = w0[ic];
                float w = w1[oc*72 + ic*9 + k];
                if (a > 0.f) wp += w * a;
                else         wq += w * (-a);
            }
            W[(oc*9 + k)*2 + 0] = wp;
            W[(oc*9 + k)*2 + 1] = wq;
            if (k == 0) {
                float beta[9];
                for (int kk = 0; kk < 9; ++kk) {
                    float s = 0.f;
                    for (int ic = 0; ic < 8; ++ic) s += b0[ic] * w1[oc*72 + ic*9 + kk];
                    beta[kk] = 65536.0f * s;   // bias doubles each of 16 iters
                }
                for (int r = 0; r < 3; ++r) {
                    W[576 + oc*4 + r] = beta[r*3] + beta[r*3+1] + beta[r*3+2]
                                      + ((r == 1) ? b1[oc] : 0.f);
                    W[704 + oc*4 + r] = beta[r*3 + 0];
                    W[832 + oc*4 + r] = beta[r*3 + 2];
                }
            }
        }
    }

    __shared__ f2 halo[2][4][2][4][64];      // [par][wave][top/bot][comp2][lane] = 32 KB
    const int tid   = threadIdx.x;
    const int lane  = tid & 63;
    const int w     = tid >> 6;              // band 0..3, 16 rows each
    const int ty    = blockIdx.x;            // 0..15
    const int plane = blockIdx.y;            // 0..7 P(img), 8..15 Q(img)
    const int colg  = lane * 8;
    const int row0g = ty*32 - 16 + w*16;     // global row of h[0]

    const float* sp = x + (plane & 7)*N_PIX;
    const float sgn = (plane >= 8) ? -1.f : 1.f;

    Row8 h[16];
    #pragma unroll
    for (int r = 0; r < 16; ++r) {
        int gy = row0g + r;
        if ((unsigned)gy < 512u) {
            const float* rp = sp + gy*512 + colg;
            float4 a = *(const float4*)rp;
            float4 b = *(const float4*)(rp + 4);
            h[r].a = make_float4(a.x*sgn, a.y*sgn, a.z*sgn, a.w*sgn);
            h[r].b = make_float4(b.x*sgn, b.y*sgn, b.z*sgn, b.w*sgn);
        } else {
            h[r].a = make_float4(INF, INF, INF, INF);
            h[r].b = h[r].a;
        }
    }

    const Row8 inf8 = { make_float4(INF,INF,INF,INF), make_float4(INF,INF,INF,INF) };
    for (int s = 0; s < 16; ++s) {
        int par = s & 1;
        halo_write(&halo[par][w][0][0][lane], h[0]);
        halo_write(&halo[par][w][1][0][lane], h[15]);
        // interior rows 1..14 before the barrier (rolling; save old h[1] for boundary)
        Row8 o1 = h[1];
        Row8 prev = h[0];
        #pragma unroll
        for (int r = 1; r <= 14; ++r) {
            Row8 tmp = h[r];
            h[r] = row_update8(prev, h[r], h[r+1]);
            prev = tmp;                      // after loop: prev = old h[14]
        }
        __syncthreads();
        Row8 up = inf8, dn = inf8;
        if (w > 0) up = halo_read(&halo[par][w-1][1][0][lane]);   // prev band old row 15
        if (w < 3) dn = halo_read(&halo[par][w+1][0][0][lane]);   // next band old row 0
        h[0]  = row_update8(up,   h[0],  o1);
        h[15] = row_update8(prev, h[15], dn);
    }

    // valid: bands 1..2 = staged rows [16,48) = global [ty*32, ty*32+32)
    if (w == 1 || w == 2) {
        float* dp = A + plane*N_PIX;
        #pragma unroll
        for (int r = 0; r < 16; ++r) {
            float* op = dp + (row0g + r)*512 + colg;
            *(float4*)op       = h[r].a;
            *(float4*)(op + 4) = h[r].b;
        }
    }
}

// ---------------------------------------------------------------- head
// Wave = one image row (64 lanes x 8 px). Weights via uniform scalar loads (no LDS);
// edge-column beta corrections applied with masked FMAs; neighbor px via DPP (fill=0
// gives the SAME-conv zero pad for free).
__global__ __launch_bounds__(256) void head_kernel(
    const float* __restrict__ A, const float* __restrict__ W,
    const float* __restrict__ w2, const float* __restrict__ b2,
    float* __restrict__ out)
{
    const int tid  = threadIdx.x;
    const int lane = tid & 63;
    const int w    = tid >> 6;
    const int img  = blockIdx.x >> 7;            // 128 blocks per image
    const int y    = (blockIdx.x & 127)*4 + w;   // wave-uniform row
    const int x0   = lane*8;

    const float* P = A + img*N_PIX;
    const float* Q = A + (8 + img)*N_PIX;

    f2 pq[3][10];
    #pragma unroll
    for (int dy = 0; dy < 3; ++dy) {
        int gy = y + dy - 1;
        if ((unsigned)gy < 512u) {               // wave-uniform branch
            const float* rp = P + gy*512 + x0;
            const float* rq = Q + gy*512 + x0;
            float4 a = *(const float4*)rp;
            float4 b = *(const float4*)(rp + 4);
            float4 c = *(const float4*)rq;
            float4 d = *(const float4*)(rq + 4);
            pq[dy][1] = (f2){a.x, c.x}; pq[dy][2] = (f2){a.y, c.y};
            pq[dy][3] = (f2){a.z, c.z}; pq[dy][4] = (f2){a.w, c.w};
            pq[dy][5] = (f2){b.x, d.x}; pq[dy][6] = (f2){b.y, d.y};
            pq[dy][7] = (f2){b.z, d.z}; pq[dy][8] = (f2){b.w, d.w};
            pq[dy][0] = (f2){dpp_shr1(b.w, 0.f), dpp_shr1(d.w, 0.f)};  // x0-1 (lane0 -> pad 0)
            pq[dy][9] = (f2){dpp_shl1(a.x, 0.f), dpp_shl1(c.x, 0.f)};  // x0+8 (lane63 -> pad 0)
        } else {
            #pragma unroll
            for (int j = 0; j < 10; ++j) pq[dy][j] = (f2){0.f, 0.f};
        }
    }

    const float ry0 = (y >= 1)   ? 1.f : 0.f;
    const float ry2 = (y <= 510) ? 1.f : 0.f;
    const float mL  = (lane == 0)  ? -1.f : 0.f;   // subtract-mask for x=0 col
    const float mR  = (lane == 63) ? -1.f : 0.f;   // subtract-mask for x=511 col

    float o[8];
    #pragma unroll
    for (int j = 0; j < 8; ++j) o[j] = 0.f;

    const f2* Wv = (const f2*)W;   // Wv[oc*9+k] = {wp,wq}, uniform offsets -> s_load
    #pragma unroll 2
    for (int oc = 0; oc < 32; ++oc) {
        f2 acc[8];
        {
            f2 wv0 = Wv[oc*9];
            #pragma unroll
            for (int j = 0; j < 8; ++j) acc[j] = wv0 * pq[0][j];
        }
        #pragma unroll
        for (int t = 1; t < 9; ++t) {
            const int ky = t / 3, kx = t - ky*3;
            f2 wv = Wv[oc*9 + t];
            #pragma unroll
            for (int j = 0; j < 8; ++j) acc[j] += wv * pq[ky][kx + j];
        }
        // bias: row sums, ry-masked
        float base = W[576 + oc*4 + 1]
                   + ry0 * W[576 + oc*4 + 0]
                   + ry2 * W[576 + oc*4 + 2];
        // edge col corrections (only lanes 0 / 63, px 0 / 7)
        float cl = W[704 + oc*4 + 1] + ry0 * W[704 + oc*4 + 0] + ry2 * W[704 + oc*4 + 2];
        float cr = W[832 + oc*4 + 1] + ry0 * W[832 + oc*4 + 0] + ry2 * W[832 + oc*4 + 2];
        float s[8];
        #pragma unroll
        for (int j = 0; j < 8; ++j) s[j] = acc[j].x + acc[j].y + base;
        s[0] = fmaf(cl, mL, s[0]);
        s[7] = fmaf(cr, mR, s[7]);
        float sc = w2[oc];
        #pragma unroll
        for (int j = 0; j < 8; ++j) o[j] += fmaxf(s[j], 0.f) * sc;
    }

    float bb = b2[0];
    float* op = out + img*N_PIX + y*512 + x0;
    *(float4*)(op)     = make_float4(o[0]+bb, o[1]+bb, o[2]+bb, o[3]+bb);
    *(float4*)(op + 4) = make_float4(o[4]+bb, o[5]+bb, o[6]+bb, o[7]+bb);
}

// ---------------------------------------------------------------- launch
extern "C" void kernel_launch(void* const* d_in, const int* in_sizes, int n_in,
                              void* d_out, int out_size, void* d_ws, size_t ws_size,
                              hipStream_t stream) {
    const float* x  = (const float*)d_in[0];
    const float* w0 = (const float*)d_in[1];
    const float* b0 = (const float*)d_in[2];
    const float* w1 = (const float*)d_in[3];
    const float* b1 = (const float*)d_in[4];
    const float* w2 = (const float*)d_in[5];
    const float* b2 = (const float*)d_in[6];
    float* out = (float*)d_out;

    float* wsf = (float*)d_ws;
    float* A = wsf;                 // 16 planes (P imgs 0..7, Q imgs 8..15), 16.8 MB
    float* W = wsf + 16*N_PIX;      // 960 floats of folded weights

    dim3 eg(16, 16);
    erode16_kernel<<<eg, 256, 0, stream>>>(x, A, w0, b0, w1, b1, W);  // 16 steps + prep

    head_kernel<<<1024, 256, 0, stream>>>(A, W, w2, b2, out);
}

// Round 11
// 125.457 us; speedup vs baseline: 1.0424x; 1.0424x over previous
//
#include <hip/hip_runtime.h>
#include <math.h>

// SDFNet: conv1x1(1->8) -> 16x (h += minpool3(h)) -> conv3x3(8->32) -> relu -> conv1x1(32->1)
//
// Factorization: erosion steps act per-channel on affine maps of x.
//   w0[c] > 0: h_c after 16 iters = w0[c]*P16(x) + b0[c]*2^16   (P = min-iterate of x)
//   w0[c] < 0: h_c = |w0[c]|*Q16 + b0[c]*2^16, Q = min-iterate of -x (pad +inf exact)
// Head = 3x3 conv over (P,Q) with folded weights (f2 -> v_pk_fma_f32), bias
// beta = 65536*sum_ic b0*w1 applied only for in-image taps (ref zero-pads h).
//
// R8: cross-lane +/-1 shifts via wave-wide DPP (old = INF/0 fill).
// R9: 2 erosion steps per barrier; prep folded into erode (best: 128.3).
// R11: head bias/edge tables precomputed per row-case (y=0 / interior / y=511) in
// prep -> per-oc bias work becomes 3 uniform s_loads (was ~14 VALU/scalar instr).

#define N_PIX (512*512)
#define INF __builtin_inff()

typedef __attribute__((ext_vector_type(2))) float f2;

// lane l gets v[l-1]; lane 0 gets `fill`   (DPP wave_shr1 = 0x138, VALU pipe)
__device__ __forceinline__ float dpp_shr1(float v, float fill) {
    return __int_as_float(__builtin_amdgcn_update_dpp(
        __float_as_int(fill), __float_as_int(v), 0x138, 0xF, 0xF, false));
}
// lane l gets v[l+1]; lane 63 gets `fill`  (DPP wave_shl1 = 0x130)
__device__ __forceinline__ float dpp_shl1(float v, float fill) {
    return __int_as_float(__builtin_amdgcn_update_dpp(
        __float_as_int(fill), __float_as_int(v), 0x130, 0xF, 0xF, false));
}

// ---------------------------------------------------------------- erosion + prep
// W layout (floats):
//   [0..575]                 f2 {wp,wq} at index (oc*9+k)  (k = ky*3+kx)
//   [576 + case*96 + oc]     D  (bias incl. b1), case: 0=y0, 1=interior, 2=y511
//   [576 + case*96 + 32+oc]  EL (x=0 column correction)
//   [576 + case*96 + 64+oc]  ER (x=511 column correction)
struct Row8 { float4 a, b; };

__device__ __forceinline__ Row8 row_update8(const Row8 up, const Row8 mid, const Row8 dn)
{
    float4 va, vb;
    va.x = fminf(fminf(up.a.x, mid.a.x), dn.a.x);
    va.y = fminf(fminf(up.a.y, mid.a.y), dn.a.y);
    va.z = fminf(fminf(up.a.z, mid.a.z), dn.a.z);
    va.w = fminf(fminf(up.a.w, mid.a.w), dn.a.w);
    vb.x = fminf(fminf(up.b.x, mid.b.x), dn.b.x);
    vb.y = fminf(fminf(up.b.y, mid.b.y), dn.b.y);
    vb.z = fminf(fminf(up.b.z, mid.b.z), dn.b.z);
    vb.w = fminf(fminf(up.b.w, mid.b.w), dn.b.w);
    float vmL = dpp_shr1(vb.w, INF);   // left neighbor vmin; lane0 -> +inf image edge
    float vmR = dpp_shl1(va.x, INF);   // right neighbor vmin; lane63 -> +inf image edge
    float tm1 = fminf(vmL, va.x);
    float t0 = fminf(va.x, va.y), t1 = fminf(va.y, va.z);
    float t2 = fminf(va.z, va.w), t3 = fminf(va.w, vb.x);
    float t4 = fminf(vb.x, vb.y), t5 = fminf(vb.y, vb.z);
    float t6 = fminf(vb.z, vb.w), t7 = fminf(vb.w, vmR);
    Row8 o;
    o.a.x = mid.a.x + fminf(tm1, t0);
    o.a.y = mid.a.y + fminf(t0, t1);
    o.a.z = mid.a.z + fminf(t1, t2);
    o.a.w = mid.a.w + fminf(t2, t3);
    o.b.x = mid.b.x + fminf(t3, t4);
    o.b.y = mid.b.y + fminf(t4, t5);
    o.b.z = mid.b.z + fminf(t5, t6);
    o.b.w = mid.b.w + fminf(t6, t7);
    return o;
}

__device__ __forceinline__ void halo_write(float* hp, const Row8& v) {
    hp[0*64]=v.a.x; hp[1*64]=v.a.y; hp[2*64]=v.a.z; hp[3*64]=v.a.w;
    hp[4*64]=v.b.x; hp[5*64]=v.b.y; hp[6*64]=v.b.z; hp[7*64]=v.b.w;
}
__device__ __forceinline__ Row8 halo_read(const float* hp) {
    Row8 v;
    v.a.x=hp[0*64]; v.a.y=hp[1*64]; v.a.z=hp[2*64]; v.a.w=hp[3*64];
    v.b.x=hp[4*64]; v.b.y=hp[5*64]; v.b.z=hp[6*64]; v.b.w=hp[7*64];
    return v;
}

__global__ __launch_bounds__(512, 2) void erode16_kernel(
    const float* __restrict__ x, float* __restrict__ A,
    const float* __restrict__ w0, const float* __restrict__ b0,
    const float* __restrict__ w1, const float* __restrict__ b1,
    float* __restrict__ W)
{
    // prep fold (one block; W consumed only by the later head dispatch)
    if (blockIdx.x == 0 && blockIdx.y == 0 && threadIdx.x < 288) {
        int tid = threadIdx.x;
        int oc = tid / 9, k = tid - oc*9;
        float wp = 0.f, wq = 0.f;
        for (int ic = 0; ic < 8; ++ic) {
            float a = w0[ic];
            float w = w1[oc*72 + ic*9 + k];
            if (a > 0.f) wp += w * a;
            else         wq += w * (-a);
        }
        W[(oc*9 + k)*2 + 0] = wp;
        W[(oc*9 + k)*2 + 1] = wq;
        if (k == 0) {
            float beta[9];
            for (int kk = 0; kk < 9; ++kk) {
                float s = 0.f;
                for (int ic = 0; ic < 8; ++ic) s += b0[ic] * w1[oc*72 + ic*9 + kk];
                beta[kk] = 65536.0f * s;   // bias doubles each of 16 iters
            }
            float R[3], L[3], Rr[3];
            for (int r = 0; r < 3; ++r) {
                R[r]  = beta[r*3] + beta[r*3+1] + beta[r*3+2];
                L[r]  = beta[r*3 + 0];
                Rr[r] = beta[r*3 + 2];
            }
            float bb = b1[oc];
            // case 0: y=0 (ky=0 row out of image) ; case 1: interior ; case 2: y=511
            W[576 + 0*96 + oc]      = bb + R[1] + R[2];
            W[576 + 0*96 + 32 + oc] = L[1] + L[2];
            W[576 + 0*96 + 64 + oc] = Rr[1] + Rr[2];
            W[576 + 1*96 + oc]      = bb + R[0] + R[1] + R[2];
            W[576 + 1*96 + 32 + oc] = L[0] + L[1] + L[2];
            W[576 + 1*96 + 64 + oc] = Rr[0] + Rr[1] + Rr[2];
            W[576 + 2*96 + oc]      = bb + R[0] + R[1];
            W[576 + 2*96 + 32 + oc] = L[0] + L[1];
            W[576 + 2*96 + 64 + oc] = Rr[0] + Rr[1];
        }
    }

    __shared__ float halo[2][8][4][8][64];   // [par][wave][{r0,r1,r6,r7}][comp][lane] = 128 KB
    const int tid   = threadIdx.x;
    const int lane  = tid & 63;
    const int w     = tid >> 6;              // band 0..7, 8 rows each
    const int ty    = blockIdx.x;            // 0..15
    const int plane = blockIdx.y;            // 0..7 P(img), 8..15 Q(img)
    const int colg  = lane * 8;
    const int row0g = ty*32 - 16 + w*8;      // global row of h[0]

    const float* sp = x + (plane & 7)*N_PIX;
    const float sgn = (plane >= 8) ? -1.f : 1.f;

    Row8 h[8];
    #pragma unroll
    for (int r = 0; r < 8; ++r) {
        int gy = row0g + r;
        if ((unsigned)gy < 512u) {
            const float* rp = sp + gy*512 + colg;
            float4 a = *(const float4*)rp;
            float4 b = *(const float4*)(rp + 4);
            h[r].a = make_float4(a.x*sgn, a.y*sgn, a.z*sgn, a.w*sgn);
            h[r].b = make_float4(b.x*sgn, b.y*sgn, b.z*sgn, b.w*sgn);
        } else {
            h[r].a = make_float4(INF, INF, INF, INF);
            h[r].b = h[r].a;
        }
    }

    const Row8 inf8 = { make_float4(INF,INF,INF,INF), make_float4(INF,INF,INF,INF) };
    for (int s = 0; s < 8; ++s) {            // 8 pairs = 16 steps
        int par = s & 1;
        halo_write(&halo[par][w][0][0][lane], h[0]);
        halo_write(&halo[par][w][1][0][lane], h[1]);
        halo_write(&halo[par][w][2][0][lane], h[6]);
        halo_write(&halo[par][w][3][0][lane], h[7]);
        // step-A interior (no halo dependency) before the barrier
        Row8 n2 = row_update8(h[1], h[2], h[3]);
        Row8 n3 = row_update8(h[2], h[3], h[4]);
        Row8 n4 = row_update8(h[3], h[4], h[5]);
        Row8 n5 = row_update8(h[4], h[5], h[6]);
        __syncthreads();
        Row8 um2 = inf8, um1 = inf8, dp0 = inf8, dp1 = inf8;
        if (w > 0) {                         // prev band's old rows 6,7 = my rows -2,-1
            um2 = halo_read(&halo[par][w-1][2][0][lane]);
            um1 = halo_read(&halo[par][w-1][3][0][lane]);
        }
        if (w < 7) {                         // next band's old rows 0,1 = my rows 8,9
            dp0 = halo_read(&halo[par][w+1][0][0][lane]);
            dp1 = halo_read(&halo[par][w+1][1][0][lane]);
        }
        // step-A boundary rows
        Row8 nm1 = row_update8(um2, um1, h[0]);
        Row8 n0  = row_update8(um1, h[0], h[1]);
        Row8 n1  = row_update8(h[0], h[1], h[2]);
        Row8 n6  = row_update8(h[5], h[6], h[7]);
        Row8 n7  = row_update8(h[6], h[7], dp0);
        Row8 n8  = row_update8(h[7], dp0, dp1);
        // step B: rows 0..7 from n[-1..8]
        h[0] = row_update8(nm1, n0, n1);
        h[1] = row_update8(n0,  n1, n2);
        h[2] = row_update8(n1,  n2, n3);
        h[3] = row_update8(n2,  n3, n4);
        h[4] = row_update8(n3,  n4, n5);
        h[5] = row_update8(n4,  n5, n6);
        h[6] = row_update8(n5,  n6, n7);
        h[7] = row_update8(n6,  n7, n8);
    }

    // valid: bands 2..5 = staged rows [16,48) = global [ty*32, ty*32+32)
    if (w >= 2 && w <= 5) {
        float* dp = A + plane*N_PIX;
        #pragma unroll
        for (int r = 0; r < 8; ++r) {
            float* op = dp + (row0g + r)*512 + colg;
            *(float4*)op       = h[r].a;
            *(float4*)(op + 4) = h[r].b;
        }
    }
}

// ---------------------------------------------------------------- head
// Wave = one image row (64 lanes x 8 px). Weights + bias tables via uniform scalar
// loads (no LDS); row-case (y=0/interior/y=511) picked once per wave; edge-column
// corrections applied with masked FMAs; neighbor px via DPP (fill=0 = zero pad).
__global__ __launch_bounds__(256) void head_kernel(
    const float* __restrict__ A, const float* __restrict__ W,
    const float* __restrict__ w2, const float* __restrict__ b2,
    float* __restrict__ out)
{
    const int tid  = threadIdx.x;
    const int lane = tid & 63;
    const int w    = tid >> 6;
    const int img  = blockIdx.x >> 7;            // 128 blocks per image
    const int y    = (blockIdx.x & 127)*4 + w;   // wave-uniform row
    const int x0   = lane*8;

    const float* P = A + img*N_PIX;
    const float* Q = A + (8 + img)*N_PIX;

    f2 pq[3][10];
    #pragma unroll
    for (int dy = 0; dy < 3; ++dy) {
        int gy = y + dy - 1;
        if ((unsigned)gy < 512u) {               // wave-uniform branch
            const float* rp = P + gy*512 + x0;
            const float* rq = Q + gy*512 + x0;
            float4 a = *(const float4*)rp;
            float4 b = *(const float4*)(rp + 4);
            float4 c = *(const float4*)rq;
            float4 d = *(const float4*)(rq + 4);
            pq[dy][1] = (f2){a.x, c.x}; pq[dy][2] = (f2){a.y, c.y};
            pq[dy][3] = (f2){a.z, c.z}; pq[dy][4] = (f2){a.w, c.w};
            pq[dy][5] = (f2){b.x, d.x}; pq[dy][6] = (f2){b.y, d.y};
            pq[dy][7] = (f2){b.z, d.z}; pq[dy][8] = (f2){b.w, d.w};
            pq[dy][0] = (f2){dpp_shr1(b.w, 0.f), dpp_shr1(d.w, 0.f)};  // x0-1 (lane0 -> pad 0)
            pq[dy][9] = (f2){dpp_shl1(a.x, 0.f), dpp_shl1(c.x, 0.f)};  // x0+8 (lane63 -> pad 0)
        } else {
            #pragma unroll
            for (int j = 0; j < 10; ++j) pq[dy][j] = (f2){0.f, 0.f};
        }
    }

    // row-case table pointer (wave-uniform): 0 = y0, 1 = interior, 2 = y511
    const int wcase = (y == 0) ? 0 : ((y == 511) ? 2 : 1);
    const float* WB = W + 576 + wcase*96;
    const float mL  = (lane == 0)  ? -1.f : 0.f;   // subtract-mask for x=0 col
    const float mR  = (lane == 63) ? -1.f : 0.f;   // subtract-mask for x=511 col

    float o[8];
    #pragma unroll
    for (int j = 0; j < 8; ++j) o[j] = 0.f;

    const f2* Wv = (const f2*)W;   // Wv[oc*9+k] = {wp,wq}, uniform offsets -> s_load
    #pragma unroll 2
    for (int oc = 0; oc < 32; ++oc) {
        f2 acc[8];
        {
            f2 wv0 = Wv[oc*9];
            #pragma unroll
            for (int j = 0; j < 8; ++j) acc[j] = wv0 * pq[0][j];
        }
        #pragma unroll
        for (int t = 1; t < 9; ++t) {
            const int ky = t / 3, kx = t - ky*3;
            f2 wv = Wv[oc*9 + t];
            #pragma unroll
            for (int j = 0; j < 8; ++j) acc[j] += wv * pq[ky][kx + j];
        }
        float base = WB[oc];          // uniform s_loads, zero VALU
        float cl   = WB[32 + oc];
        float cr   = WB[64 + oc];
        float s[8];
        #pragma unroll
        for (int j = 0; j < 8; ++j) s[j] = acc[j].x + acc[j].y + base;
        s[0] = fmaf(cl, mL, s[0]);
        s[7] = fmaf(cr, mR, s[7]);
        float sc = w2[oc];
        #pragma unroll
        for (int j = 0; j < 8; ++j) o[j] += fmaxf(s[j], 0.f) * sc;
    }

    float bb = b2[0];
    float* op = out + img*N_PIX + y*512 + x0;
    *(float4*)(op)     = make_float4(o[0]+bb, o[1]+bb, o[2]+bb, o[3]+bb);
    *(float4*)(op + 4) = make_float4(o[4]+bb, o[5]+bb, o[6]+bb, o[7]+bb);
}

// ---------------------------------------------------------------- launch
extern "C" void kernel_launch(void* const* d_in, const int* in_sizes, int n_in,
                              void* d_out, int out_size, void* d_ws, size_t ws_size,
                              hipStream_t stream) {
    const float* x  = (const float*)d_in[0];
    const float* w0 = (const float*)d_in[1];
    const float* b0 = (const float*)d_in[2];
    const float* w1 = (const float*)d_in[3];
    const float* b1 = (const float*)d_in[4];
    const float* w2 = (const float*)d_in[5];
    const float* b2 = (const float*)d_in[6];
    float* out = (float*)d_out;

    float* wsf = (float*)d_ws;
    float* A = wsf;                 // 16 planes (P imgs 0..7, Q imgs 8..15), 16.8 MB
    float* W = wsf + 16*N_PIX;      // 864 floats of folded weights

    dim3 eg(16, 16);
    erode16_kernel<<<eg, 512, 0, stream>>>(x, A, w0, b0, w1, b1, W);  // 16 steps + prep

    head_kernel<<<1024, 256, 0, stream>>>(A, W, w2, b2, out);
}